// Round 8
// baseline (998.514 us; speedup 1.0000x reference)
//
#include <hip/hip_runtime.h>

typedef _Float16 f16;
typedef __attribute__((ext_vector_type(8))) _Float16 f16x8;
typedef __attribute__((ext_vector_type(4))) float    f32x4;

#define B_ROWS 16384
#define MPAD   17408   // 16384 + 8 clusters * 128-row tile padding
#define MTILES 136
#define NBLK   64      // B_ROWS / 256

typedef __attribute__((address_space(1))) void as1_void;
typedef __attribute__((address_space(3))) void as3_void;

__device__ __forceinline__ void gl_lds16(const void* g, void* l) {
    __builtin_amdgcn_global_load_lds((const as1_void*)g, (as3_void*)l, 16, 0, 0);
}
template<typename T>
__device__ __forceinline__ void st_nt(T* p, T v) { __builtin_nontemporal_store(v, p); }

struct Seg   { const float* s; f16* d; int K, N, nx, ny; long sCS, dCS; };
struct GemmL { const f16* A; const f16* Wt; const float* bias; f16* OutH; float* OutF; int K, N, flags; };
// flags: 1=GATHER  2=PERW  4=RELU  8=EPI1(fp32 rowmap-scatter)  16=EPI2(reparam)

struct Mega {
    Seg   sg[10];      // 1..9 used (weight transposes)
    GemmL L[8];
    const float* x; f16* xh;
    const int* lbl; const float* mb; const float* lb; float* bz; f16* zerob;
    int* blockhist; int* blockbase; int* offs; int* tilec; int* rowmap;
    const float* eps; int* done;
};

// ---- software grid barrier.  Deadlock-safe because grid is sized by the occupancy API with
// >=2x co-residency slack (32KB LDS -> ~5 blocks/CU capacity, grid <= 512).  Spin target is
// gridDim.x, so ANY launched grid size is correct.  Release: __syncthreads drains each wave's
// stores -> tid0 __threadfence (agent acq_rel: buffer_wbl2) -> agent-scope add.  Acquire:
// relaxed spin -> __syncthreads -> all-thread __threadfence (buffer_inv).  Handles per-XCD
// L2 non-coherence (G16).
__device__ __forceinline__ void phase_barrier(int p, int* done) {
    __syncthreads();
    if (threadIdx.x == 0) {
        __threadfence();
        __hip_atomic_fetch_add(&done[p], 1, __ATOMIC_RELEASE, __HIP_MEMORY_SCOPE_AGENT);
        while (__hip_atomic_load(&done[p], __ATOMIC_RELAXED, __HIP_MEMORY_SCOPE_AGENT) < (int)gridDim.x)
            __builtin_amdgcn_s_sleep(8);
    }
    __syncthreads();
    __threadfence();
}

// ---- phase bodies (32KB smem handed in; each does its own __syncthreads around smem use) ----

__device__ __forceinline__ void prep_body(char* smemraw, int b, const int* __restrict__ lbl,
        int* __restrict__ blockhist, int* __restrict__ rowmap,
        const float* __restrict__ mb_, const float* __restrict__ lb_,
        float* __restrict__ bz, f16* __restrict__ zerob) {
    int* h = (int*)smemraw;
    int t = threadIdx.x;
    int i = b * 256 + t;
    rowmap[i] = -1;
    if (b < NBLK) {
        __syncthreads();
        if (t < 8) h[t] = 0;
        __syncthreads();
        atomicAdd(&h[lbl[i]], 1);      // LDS atomic
        __syncthreads();
        if (t < 8) blockhist[b * 8 + t] = h[t];
    } else if (b == NBLK) {
        if (t < 64) zerob[t] = (f16)0.f;
        if (t < 64) bz[t] = mb_[t];
        else if (t < 128) bz[t] = lb_[t - 64];
    }
}

__device__ __forceinline__ void offsets_body(char* smemraw, const int* __restrict__ blockhist,
        int* __restrict__ offs, int* __restrict__ tilec, int* __restrict__ blockbase) {
    int* tot = (int*)smemraw;
    int* so  = tot + 8;
    int t = threadIdx.x;
    __syncthreads();
    if (t < 8) {
        int s = 0;
        for (int b = 0; b < NBLK; ++b) s += blockhist[b * 8 + t];
        tot[t] = s;
    }
    __syncthreads();
    if (t == 0) {
        int o = 0;
        for (int c = 0; c < 8; ++c) { so[c] = o; o += (tot[c] + 127) & ~127; }
        so[8] = o;
        for (int c = 0; c < 9; ++c) offs[c] = so[c];
    }
    __syncthreads();
    if (t < 8) {
        int run = so[t];
        for (int b = 0; b < NBLK; ++b) {
            blockbase[b * 8 + t] = run;
            run += blockhist[b * 8 + t];
        }
    }
    if (t < MTILES) {
        int row = t * 128, c = 7;
        for (int cc = 0; cc < 8; ++cc)
            if (row >= so[cc] && row < so[cc + 1]) c = cc;
        tilec[t] = c;
    }
}

__device__ __forceinline__ void scatter_body(char* smemraw, int b, const int* __restrict__ lbl,
        const int* __restrict__ blockbase, int* __restrict__ rowmap) {
    int* cur = (int*)smemraw;
    __syncthreads();
    if (threadIdx.x < 8) cur[threadIdx.x] = blockbase[b * 8 + threadIdx.x];
    __syncthreads();
    int i = b * 256 + threadIdx.x;
    int c = lbl[i];
    int pos = atomicAdd(&cur[c], 1);   // LDS atomic
    rowmap[pos] = i;
}

// 64x64 weight transpose tile: [K,N] fp32 -> [N,K] f16, full 128B write segments (R4-proven)
__device__ __forceinline__ void trans_tile(char* smemraw, Seg sg, int lb) {
    float (*ld)[64] = (float(*)[64])smemraw;   // 16KB of the 32KB
    int t = threadIdx.x;
    int nxy = sg.nx * sg.ny;
    int z = lb / nxy; int r = lb - z * nxy;
    int by = r / sg.nx; int bx = r - by * sg.nx;
    const float* src = sg.s + (size_t)z * sg.sCS;
    f16* dst = sg.d + (size_t)z * sg.dCS;
    int n0 = bx * 64, k0 = by * 64;
    int cr = t >> 4, cc = (t & 15) * 4;
    __syncthreads();                       // previous smem user done
    #pragma unroll
    for (int i = 0; i < 4; ++i) {
        int rr = cr + 16 * i;
        float4 v = *(const float4*)(src + (size_t)(k0 + rr) * sg.N + n0 + cc);
        *(float4*)&ld[rr][(((cc >> 2) ^ (rr & 15)) << 2)] = v;
    }
    __syncthreads();
    #pragma unroll
    for (int p = 0; p < 2; ++p) {
        int G = p * 256 + t;
        int n = G >> 3, gg = G & 7;
        f16x8 o;
        #pragma unroll
        for (int j = 0; j < 8; ++j) {
            int kk = gg * 8 + j;
            o[j] = (f16)ld[kk][(((n >> 2) ^ (kk & 15)) << 2) | (n & 3)];
        }
        *(f16x8*)(dst + (size_t)(n0 + n) * sg.K + k0 + gg * 8) = o;
    }
}

// 128x128 BK=32 MFMA gemm tile (R3-proven layout) + counted vmcnt(4) (R4-proven schedule).
// LDS: 2 x (A 8KB + B 8KB) = 32KB.  Granule swizzle: slot = sg ^ ((row>>1)&3).
__device__ __forceinline__ void gemm_tile(char* smem, int vt, GemmL L,
        const int* __restrict__ rowmap, const int* __restrict__ tilec,
        const f16* __restrict__ zerobuf, const float* __restrict__ eps)
{
    const int tid  = threadIdx.x;
    const int wave = tid >> 6;
    const int lane = tid & 63;
    const int xcd = vt & 7, jj = vt >> 3;
    const int tm = (jj % 17) * 8 + xcd;    // 0..135 (vt&7 == bid&7 under grid-stride: XCD-stable)
    const int tn = jj / 17;
    const int r0 = tm * 128, n0 = tn * 128;
    const int K = L.K, N = L.N;

    const f16* wb = L.Wt;
    const float* bb = L.bias;
    if (L.flags & 2) { int c = tilec[tm]; wb += (size_t)c * K * N; bb += (size_t)c * N; }

    const int srow = tid >> 2, sg = tid & 3;       // srow 0..63
    const int xk16 = (sg ^ ((srow >> 1) & 3)) * 16;
    const size_t rowB = (size_t)K * 2;

    const char* pa[2]; size_t stepA[2];
    #pragma unroll
    for (int p = 0; p < 2; ++p) {
        int gr = r0 + p * 64 + srow;
        if (L.flags & 1) {
            int g = rowmap[gr];
            if (g >= 0) { pa[p] = (const char*)(L.A + (size_t)g * K) + xk16; stepA[p] = 64; }
            else        { pa[p] = (const char*)zerobuf;                      stepA[p] = 0;  }
        } else {
            pa[p] = (const char*)(L.A + (size_t)gr * K) + xk16; stepA[p] = 64;
        }
    }
    const char* pb = (const char*)(wb + (size_t)(n0 + srow) * K) + xk16;
    const size_t pbOff = 64 * rowB;

    const int mb = (wave >> 1) * 64, nb = (wave & 1) * 64;
    const int quad = lane >> 4, r16 = lane & 15;
    const int off  = (quad ^ ((r16 >> 1) & 3)) * 16;

    float bv[4];
    #pragma unroll
    for (int j = 0; j < 4; ++j) bv[j] = bb[n0 + nb + j * 16 + r16];

    f32x4 acc[4][4];
    #pragma unroll
    for (int i = 0; i < 4; ++i)
        #pragma unroll
        for (int j = 0; j < 4; ++j)
            acc[i][j] = (f32x4){0.f, 0.f, 0.f, 0.f};

    auto stage = [&](char* dst) {
        gl_lds16(pa[0],        dst         + wave * 1024);
        gl_lds16(pa[1],        dst + 4096  + wave * 1024);
        gl_lds16(pb,           dst + 8192  + wave * 1024);
        gl_lds16(pb + pbOff,   dst + 12288 + wave * 1024);
        pa[0] += stepA[0]; pa[1] += stepA[1];
        pb += 64;
    };
    auto compute = [&](const char* base) {
        const char* lA = base;
        const char* lB = base + 8192;
        f16x8 af[4], bf[4];
        #pragma unroll
        for (int i = 0; i < 4; ++i)
            af[i] = *(const f16x8*)(lA + (mb + i * 16 + r16) * 64 + off);
        #pragma unroll
        for (int j = 0; j < 4; ++j)
            bf[j] = *(const f16x8*)(lB + (nb + j * 16 + r16) * 64 + off);
        #pragma unroll
        for (int i = 0; i < 4; ++i)
            #pragma unroll
            for (int j = 0; j < 4; ++j)
                acc[i][j] = __builtin_amdgcn_mfma_f32_16x16x32_f16(af[i], bf[j], acc[i][j], 0, 0, 0);
    };

    __syncthreads();                       // previous tile/phase done with smem

    const int nk = K >> 5;
    stage(smem);
    int cur = 0;
    for (int kb = 0; kb < nk - 1; ++kb) {
        stage(smem + ((cur ^ 1) << 14));                   // +4 loads (next buffer)
        asm volatile("s_waitcnt vmcnt(4)" ::: "memory");   // own cur-buffer loads landed
        __builtin_amdgcn_s_barrier();                      // all waves' cur loads landed
        compute(smem + (cur << 14));
        __builtin_amdgcn_s_barrier();                      // cur fully read
        cur ^= 1;
    }
    asm volatile("s_waitcnt vmcnt(0)" ::: "memory");
    __builtin_amdgcn_s_barrier();
    compute(smem + (cur << 14));

    if (L.flags & 16) {                    // EPI2: reparameterize from staged [mu|lv] tile (32KB)
        __syncthreads();
        #pragma unroll
        for (int i = 0; i < 4; ++i) {
            #pragma unroll
            for (int r = 0; r < 4; ++r) {
                int lr = mb + i * 16 + quad * 4 + r;
                #pragma unroll
                for (int j = 0; j < 4; ++j) {
                    int lc = nb + j * 16 + r16;
                    float v = acc[i][j][r] + bv[j];
                    *(f16*)(smem + lr * 256 + ((((lc >> 3) ^ (lr & 7))) << 4) + ((lc & 7) << 1)) = (f16)v;
                }
            }
        }
        __syncthreads();
        const int col = tid & 63;
        const int rb  = tid >> 6;
        for (int rr = 0; rr < 32; ++rr) {
            int row = rb * 32 + rr;
            int g = rowmap[r0 + row];
            float e = (g >= 0) ? eps[(size_t)g * 64 + col] : 0.f;
            float mu = (float)*(const f16*)(smem + row * 256 + ((((col >> 3) ^ (row & 7))) << 4) + ((col & 7) << 1));
            int c2 = col + 64;
            float lv = (float)*(const f16*)(smem + row * 256 + ((((c2 >> 3) ^ (row & 7))) << 4) + ((c2 & 7) << 1));
            st_nt(&L.OutH[(size_t)(r0 + row) * 64 + col], (f16)(mu + expf(0.5f * lv) * e));
        }
        return;
    }

    #pragma unroll
    for (int i = 0; i < 4; ++i) {
        #pragma unroll
        for (int r = 0; r < 4; ++r) {
            int orow = r0 + mb + i * 16 + quad * 4 + r;
            int g = 0;
            if (L.flags & 8) g = rowmap[orow];
            #pragma unroll
            for (int j = 0; j < 4; ++j) {
                int ocol = n0 + nb + j * 16 + r16;
                float v = acc[i][j][r] + bv[j];
                if (L.flags & 4) v = fmaxf(v, 0.f);
                if (L.flags & 8) {
                    if (g >= 0) st_nt(&L.OutF[(size_t)g * N + ocol], v);
                } else {
                    st_nt(&L.OutH[(size_t)orow * N + ocol], (f16)v);
                }
            }
        }
    }
}

// ---------------- the megakernel: whole net, 11 phases, soft grid barriers ----------------

__global__ __launch_bounds__(256) void k_zero(int* done) {
    if (threadIdx.x < 16) done[threadIdx.x] = 0;
}

__global__ __launch_bounds__(256) void megak(Mega M) {
    __shared__ __align__(16) char smem[32768];
    const int bid = blockIdx.x;
    const int t = threadIdx.x;
    const int G = gridDim.x;

    // P0: rowmap-init+hist (68) | x cvt (4096) | w0t transpose (128)
    for (int vt = bid; vt < 68 + 4096 + 128; vt += G) {
        if (vt < 68) {
            prep_body(smem, vt, M.lbl, M.blockhist, M.rowmap, M.mb, M.lb, M.bz, M.zerob);
        } else if (vt < 68 + 4096) {
            size_t i = (size_t)(vt - 68) * 256 + t;
            float4 a = ((const float4*)M.x)[2 * i];
            float4 b = ((const float4*)M.x)[2 * i + 1];
            f16x8 o = {(f16)a.x, (f16)a.y, (f16)a.z, (f16)a.w,
                       (f16)b.x, (f16)b.y, (f16)b.z, (f16)b.w};
            st_nt(&((f16x8*)M.xh)[i], o);
        } else {
            trans_tile(smem, M.sg[1], vt - (68 + 4096));
        }
    }
    phase_barrier(0, M.done);

    // P1: offsets (1) + small weight transposes (w2t 32, mu 4, lv 4, wd0t 32, wd1t 32)
    for (int vt = bid; vt < 105; vt += G) {
        if (vt == 0)       offsets_body(smem, M.blockhist, M.offs, M.tilec, M.blockbase);
        else if (vt < 33)  trans_tile(smem, M.sg[3], vt - 1);
        else if (vt < 37)  trans_tile(smem, M.sg[4], vt - 33);
        else if (vt < 41)  trans_tile(smem, M.sg[5], vt - 37);
        else if (vt < 73)  trans_tile(smem, M.sg[6], vt - 41);
        else               trans_tile(smem, M.sg[7], vt - 73);
    }
    phase_barrier(1, M.done);

    // P2: scatter (64)
    for (int vt = bid; vt < 64; vt += G)
        scatter_body(smem, vt, M.lbl, M.blockbase, M.rowmap);
    phase_barrier(2, M.done);

    // P3: wut transpose (1024, needed by L2) + L1 gemm (1088) + wd2t (1024) + wft (1024)
    for (int vt = bid; vt < 1024 + 1088 + 1024 + 1024; vt += G) {
        if (vt < 1024)       trans_tile(smem, M.sg[2], vt);
        else if (vt < 2112)  gemm_tile(smem, vt - 1024, M.L[0], M.rowmap, M.tilec, M.zerob, M.eps);
        else if (vt < 3136)  trans_tile(smem, M.sg[8], vt - 2112);
        else                 trans_tile(smem, M.sg[9], vt - 3136);
    }
    phase_barrier(3, M.done);

    // P4..P10: remaining layers
    for (int vt = bid; vt < 544; vt += G)  gemm_tile(smem, vt, M.L[1], M.rowmap, M.tilec, M.zerob, M.eps);
    phase_barrier(4, M.done);
    for (int vt = bid; vt < 272; vt += G)  gemm_tile(smem, vt, M.L[2], M.rowmap, M.tilec, M.zerob, M.eps);
    phase_barrier(5, M.done);
    for (int vt = bid; vt < 136; vt += G)  gemm_tile(smem, vt, M.L[3], M.rowmap, M.tilec, M.zerob, M.eps);  // EPI2
    phase_barrier(6, M.done);
    for (int vt = bid; vt < 272; vt += G)  gemm_tile(smem, vt, M.L[4], M.rowmap, M.tilec, M.zerob, M.eps);
    phase_barrier(7, M.done);
    for (int vt = bid; vt < 544; vt += G)  gemm_tile(smem, vt, M.L[5], M.rowmap, M.tilec, M.zerob, M.eps);
    phase_barrier(8, M.done);
    for (int vt = bid; vt < 1088; vt += G) gemm_tile(smem, vt, M.L[6], M.rowmap, M.tilec, M.zerob, M.eps);
    phase_barrier(9, M.done);
    for (int vt = bid; vt < 544; vt += G)  gemm_tile(smem, vt, M.L[7], M.rowmap, M.tilec, M.zerob, M.eps);  // EPI1 -> out
}

// ---------------- launch ----------------

extern "C" void kernel_launch(void* const* d_in, const int* in_sizes, int n_in,
                              void* d_out, int out_size, void* d_ws, size_t ws_size,
                              hipStream_t stream) {
    const float* x      = (const float*)d_in[0];
    const int*   lbl    = (const int*)  d_in[1];
    const float* eps    = (const float*)d_in[2];
    const float* enc_W0 = (const float*)d_in[3];
    const float* enc_b0 = (const float*)d_in[4];
    const float* enc_Wu = (const float*)d_in[5];
    const float* enc_bu = (const float*)d_in[6];
    const float* enc_W2 = (const float*)d_in[7];
    const float* enc_b2 = (const float*)d_in[8];
    const float* mu_W   = (const float*)d_in[9];
    const float* mu_b   = (const float*)d_in[10];
    const float* lv_W   = (const float*)d_in[11];
    const float* lv_b   = (const float*)d_in[12];
    const float* dWu0   = (const float*)d_in[13];
    const float* dbu0   = (const float*)d_in[14];
    const float* dW1    = (const float*)d_in[15];
    const float* db1    = (const float*)d_in[16];
    const float* dWu2   = (const float*)d_in[17];
    const float* dbu2   = (const float*)d_in[18];
    const float* finW   = (const float*)d_in[19];
    const float* finb   = (const float*)d_in[20];
    float* out = (float*)d_out;
    (void)in_sizes; (void)n_in; (void)out_size; (void)ws_size;

    char* base = (char*)d_ws;
    size_t off = 0;
    auto alloc = [&](size_t bytes) { char* r = base + off; off = (off + bytes + 255) & ~(size_t)255; return r; };
    f16* xh     = (f16*)alloc((size_t)B_ROWS * 512 * 2);
    f16* buf1   = (f16*)alloc((size_t)MPAD * 1024 * 2);  // h1 / h6
    f16* buf2   = (f16*)alloc((size_t)MPAD * 512 * 2);   // h2 / h5
    f16* buf3   = (f16*)alloc((size_t)MPAD * 256 * 2);   // h3 / h4
    f16* zb     = (f16*)alloc((size_t)MPAD * 64 * 2);
    f16* w0t    = (f16*)alloc(1024ul * 512 * 2);
    f16* wut    = (f16*)alloc(8ul * 512 * 1024 * 2);
    f16* w2t    = (f16*)alloc(256ul * 512 * 2);
    f16* wzt    = (f16*)alloc(128ul * 256 * 2);
    f16* wd0t   = (f16*)alloc(8ul * 256 * 64 * 2);
    f16* wd1t   = (f16*)alloc(512ul * 256 * 2);
    f16* wd2t   = (f16*)alloc(8ul * 1024 * 512 * 2);
    f16* wft    = (f16*)alloc(8ul * 512 * 1024 * 2);
    float* bz   = (float*)alloc(128 * 4);
    int* rowmap = (int*)alloc(MPAD * 4);
    int* blockhist = (int*)alloc(NBLK * 8 * 4);
    int* blockbase = (int*)alloc(NBLK * 8 * 4);
    int* offs   = (int*)alloc(64);
    int* tilec  = (int*)alloc(MTILES * 4);
    f16* zerob  = (f16*)alloc(256);
    int* done   = (int*)alloc(64);

    Mega M;
    // transpose segments: [K,N] fp32 -> [N,K] f16; nx = N/64, ny = K/64
    M.sg[1] = Seg{enc_W0, w0t, 512, 1024, 16, 8, 0, 0};
    M.sg[2] = Seg{enc_Wu, wut, 1024, 512, 8, 16, 1024l * 512, 512l * 1024};
    M.sg[3] = Seg{enc_W2, w2t, 512, 256, 4, 8, 0, 0};
    M.sg[4] = Seg{mu_W, wzt, 256, 64, 1, 4, 0, 0};
    M.sg[5] = Seg{lv_W, wzt + 64 * 256, 256, 64, 1, 4, 0, 0};
    M.sg[6] = Seg{dWu0, wd0t, 64, 256, 4, 1, 64l * 256, 256l * 64};
    M.sg[7] = Seg{dW1, wd1t, 256, 512, 8, 4, 0, 0};
    M.sg[8] = Seg{dWu2, wd2t, 512, 1024, 16, 8, 512l * 1024, 1024l * 512};
    M.sg[9] = Seg{finW, wft, 1024, 512, 8, 16, 1024l * 512, 512l * 1024};
    M.sg[0] = Seg{nullptr, nullptr, 0, 0, 0, 0, 0, 0};
    // layers: flags 1=GATHER 2=PERW 4=RELU 8=EPI1 16=EPI2
    M.L[0] = GemmL{xh,   w0t,  enc_b0, buf1, nullptr, 512, 1024, 1 | 4};
    M.L[1] = GemmL{buf1, wut,  enc_bu, buf2, nullptr, 1024, 512, 2 | 4};
    M.L[2] = GemmL{buf2, w2t,  enc_b2, buf3, nullptr, 512, 256, 4};
    M.L[3] = GemmL{buf3, wzt,  bz,     zb,   nullptr, 256, 128, 16};
    M.L[4] = GemmL{zb,   wd0t, dbu0,   buf3, nullptr, 64, 256, 2 | 4};
    M.L[5] = GemmL{buf3, wd1t, db1,    buf2, nullptr, 256, 512, 4};
    M.L[6] = GemmL{buf2, wd2t, dbu2,   buf1, nullptr, 512, 1024, 2 | 4};
    M.L[7] = GemmL{buf1, wft,  finb,   nullptr, out,  1024, 512, 2 | 8};
    M.x = x; M.xh = xh;
    M.lbl = lbl; M.mb = mu_b; M.lb = lv_b; M.bz = bz; M.zerob = zerob;
    M.blockhist = blockhist; M.blockbase = blockbase; M.offs = offs;
    M.tilec = tilec; M.rowmap = rowmap;
    M.eps = eps; M.done = done;

    // grid sized by the runtime occupancy model, capped at 512; >=2x co-residency slack at
    // 32KB LDS (~5 blocks/CU capacity).  Grid-stride loops + gridDim-based barrier make any
    // grid size correct.
    int maxb = 0;
    if (hipOccupancyMaxActiveBlocksPerMultiprocessor(&maxb, megak, 256, 0) != hipSuccess || maxb < 1)
        maxb = 1;
    int grid = maxb * 256;
    if (grid > 512) grid = 512;

    k_zero<<<1, 64, 0, stream>>>(done);
    megak<<<grid, 256, 0, stream>>>(M);
}